// Round 1
// baseline (789.011 us; speedup 1.0000x reference)
//
#include <hip/hip_runtime.h>
#include <math.h>

#define N_NODES 20000
#define N_EDGES 200000
#define D_IN 32
#define D_H 32
#define D_OUT 8
#define E_DIM 16

__device__ __forceinline__ float elu_f(float v) {
    return v > 0.0f ? v : expm1f(v);
}

// ---------------- degree ----------------
__global__ __launch_bounds__(256)
void deg_kernel(const int* __restrict__ dst, float* __restrict__ deg) {
    int e = blockIdx.x * 256 + threadIdx.x;
    if (e < N_EDGES) atomicAdd(&deg[dst[e]], 1.0f);
}

// ---------------- edge kernel: fused edge-MLP + theta + matvec + scatter ----------------
__global__ __launch_bounds__(256)
void edge_kernel(const float* __restrict__ xin,        // [N, 32]
                 const float* __restrict__ edge_attr,  // [E, 16]
                 const int* __restrict__ src,
                 const int* __restrict__ dst,
                 const float* __restrict__ w1,         // [16,16]
                 const float* __restrict__ b1,         // [16]
                 const float* __restrict__ w2,         // [16,1024]
                 const float* __restrict__ b2,         // [1024]
                 float* __restrict__ agg)              // [N, 32] (atomic accum)
{
    __shared__ float w2_s[E_DIM][D_IN * D_H];  // 64 KB
    __shared__ float b2_s[D_IN * D_H];         // 4 KB
    __shared__ float w1_s[E_DIM * E_DIM];      // 1 KB
    __shared__ float b1_s[E_DIM];

    const int t = threadIdx.x;
    for (int i = t; i < (E_DIM * D_IN * D_H) / 4; i += 256)
        ((float4*)w2_s)[i] = ((const float4*)w2)[i];
    for (int i = t; i < D_IN * D_H; i += 256) b2_s[i] = b2[i];
    for (int i = t; i < E_DIM * E_DIM; i += 256) w1_s[i] = w1[i];
    if (t < E_DIM) b1_s[t] = b1[t];
    __syncthreads();

    const int e = blockIdx.x * 256 + t;
    if (e >= N_EDGES) return;

    // --- edge MLP: h_e = elu(ea @ w1 + b1) ---
    float ea[E_DIM];
    {
        const float4* eg = (const float4*)(edge_attr + (size_t)e * E_DIM);
        float4* eav = (float4*)ea;
        eav[0] = eg[0]; eav[1] = eg[1]; eav[2] = eg[2]; eav[3] = eg[3];
    }
    float he[E_DIM];
    #pragma unroll
    for (int k = 0; k < E_DIM; ++k) {
        float a = b1_s[k];
        #pragma unroll
        for (int j = 0; j < E_DIM; ++j) a += ea[j] * w1_s[j * E_DIM + k];
        he[k] = elu_f(a);
    }

    // --- gather source features ---
    const int s = src[e];
    float xs[D_IN];
    {
        const float4* xg = (const float4*)(xin + (size_t)s * D_IN);
        float4* xsv = (float4*)xs;
        #pragma unroll
        for (int i = 0; i < D_IN / 4; ++i) xsv[i] = xg[i];
    }

    // --- msg[o] = sum_i xs[i] * theta[i][o], theta[i][o] = sum_k he[k]*w2[k][i*32+o] + b2[i*32+o] ---
    const int d = dst[e];
    float* aggp = agg + (size_t)d * D_H;
    #pragma unroll 1
    for (int og = 0; og < D_H / 4; ++og) {
        float acc0 = 0.f, acc1 = 0.f, acc2 = 0.f, acc3 = 0.f;
        #pragma unroll 4
        for (int i = 0; i < D_IN; ++i) {
            float4 th = *(const float4*)&b2_s[i * D_H + og * 4];
            #pragma unroll
            for (int k = 0; k < E_DIM; ++k) {
                const float4 w4 = *(const float4*)&w2_s[k][i * D_H + og * 4];
                th.x += he[k] * w4.x;
                th.y += he[k] * w4.y;
                th.z += he[k] * w4.z;
                th.w += he[k] * w4.w;
            }
            const float xi = xs[i];
            acc0 += xi * th.x; acc1 += xi * th.y; acc2 += xi * th.z; acc3 += xi * th.w;
        }
        atomicAdd(&aggp[og * 4 + 0], acc0);
        atomicAdd(&aggp[og * 4 + 1], acc1);
        atomicAdd(&aggp[og * 4 + 2], acc2);
        atomicAdd(&aggp[og * 4 + 3], acc3);
    }
}

// ---------------- node kernel: out = elu(agg*inv + x@root + bias) ----------------
template<bool APPLY_ELU>
__global__ __launch_bounds__(256)
void node_kernel(const float* __restrict__ xin,   // [N,32]
                 const float* __restrict__ agg,   // [N,32]
                 const float* __restrict__ deg,   // [N]
                 const float* __restrict__ root,  // [32,32]
                 const float* __restrict__ bias,  // [32]
                 float* __restrict__ out)         // [N,32]
{
    __shared__ float root_s[D_IN * D_H];
    __shared__ float bias_s[D_H];
    const int t = threadIdx.x;
    for (int i = t; i < D_IN * D_H; i += 256) root_s[i] = root[i];
    if (t < D_H) bias_s[t] = bias[t];
    __syncthreads();

    const int n = blockIdx.x * 256 + t;
    if (n >= N_NODES) return;

    float xs[D_IN];
    {
        const float4* xg = (const float4*)(xin + (size_t)n * D_IN);
        float4* xsv = (float4*)xs;
        #pragma unroll
        for (int i = 0; i < D_IN / 4; ++i) xsv[i] = xg[i];
    }
    const float inv = 1.0f / fmaxf(deg[n], 1.0f);
    const float4* av = (const float4*)(agg + (size_t)n * D_H);
    float4* ov = (float4*)(out + (size_t)n * D_H);
    #pragma unroll 1
    for (int jg = 0; jg < D_H / 4; ++jg) {
        const float4 a = av[jg];
        float r0 = bias_s[jg * 4 + 0] + a.x * inv;
        float r1 = bias_s[jg * 4 + 1] + a.y * inv;
        float r2 = bias_s[jg * 4 + 2] + a.z * inv;
        float r3 = bias_s[jg * 4 + 3] + a.w * inv;
        #pragma unroll
        for (int i = 0; i < D_IN; ++i) {
            const float4 w4 = *(const float4*)&root_s[i * D_H + jg * 4];
            const float xi = xs[i];
            r0 += xi * w4.x; r1 += xi * w4.y; r2 += xi * w4.z; r3 += xi * w4.w;
        }
        if (APPLY_ELU) { r0 = elu_f(r0); r1 = elu_f(r1); r2 = elu_f(r2); r3 = elu_f(r3); }
        float4 rv; rv.x = r0; rv.y = r1; rv.z = r2; rv.w = r3;
        ov[jg] = rv;
    }
}

// ---------------- classifier: out = h @ cls_w + cls_b ----------------
__global__ __launch_bounds__(256)
void cls_kernel(const float* __restrict__ h,     // [N,32]
                const float* __restrict__ w,     // [32,8]
                const float* __restrict__ b,     // [8]
                float* __restrict__ out)         // [N,8]
{
    __shared__ float w_s[D_H * D_OUT];
    __shared__ float b_s[D_OUT];
    const int t = threadIdx.x;
    if (t < D_H * D_OUT) w_s[t] = w[t];
    if (t < D_OUT) b_s[t] = b[t];
    __syncthreads();

    const int n = blockIdx.x * 256 + t;
    if (n >= N_NODES) return;

    float xs[D_H];
    {
        const float4* xg = (const float4*)(h + (size_t)n * D_H);
        float4* xsv = (float4*)xs;
        #pragma unroll
        for (int i = 0; i < D_H / 4; ++i) xsv[i] = xg[i];
    }
    float o[D_OUT];
    #pragma unroll
    for (int j = 0; j < D_OUT; ++j) {
        float a = b_s[j];
        #pragma unroll
        for (int i = 0; i < D_H; ++i) a += xs[i] * w_s[i * D_OUT + j];
        o[j] = a;
    }
    float4* ov = (float4*)(out + (size_t)n * D_OUT);
    ov[0] = *(float4*)&o[0];
    ov[1] = *(float4*)&o[4];
}

extern "C" void kernel_launch(void* const* d_in, const int* in_sizes, int n_in,
                              void* d_out, int out_size, void* d_ws, size_t ws_size,
                              hipStream_t stream)
{
    const float* x         = (const float*)d_in[0];
    const float* edge_attr = (const float*)d_in[1];
    const int*   edge_index= (const int*)d_in[2];
    const float* w1_0 = (const float*)d_in[3];
    const float* b1_0 = (const float*)d_in[4];
    const float* w2_0 = (const float*)d_in[5];
    const float* b2_0 = (const float*)d_in[6];
    const float* root_0 = (const float*)d_in[7];
    const float* bias_0 = (const float*)d_in[8];
    const float* w1_1 = (const float*)d_in[9];
    const float* b1_1 = (const float*)d_in[10];
    const float* w2_1 = (const float*)d_in[11];
    const float* b2_1 = (const float*)d_in[12];
    const float* root_1 = (const float*)d_in[13];
    const float* bias_1 = (const float*)d_in[14];
    const float* cls_w = (const float*)d_in[15];
    const float* cls_b = (const float*)d_in[16];

    const int* src = edge_index;
    const int* dst = edge_index + N_EDGES;

    float* deg = (float*)d_ws;                 // [N]
    float* agg = deg + N_NODES;                // [N,32]
    float* h   = agg + (size_t)N_NODES * D_H;  // [N,32]
    float* h2  = h   + (size_t)N_NODES * D_H;  // [N,32]

    const int EB = (N_EDGES + 255) / 256;
    const int NB = (N_NODES + 255) / 256;

    // zero deg + agg (contiguous)
    hipMemsetAsync(deg, 0, (N_NODES + (size_t)N_NODES * D_H) * sizeof(float), stream);

    deg_kernel<<<EB, 256, 0, stream>>>(dst, deg);

    // layer 0
    edge_kernel<<<EB, 256, 0, stream>>>(x, edge_attr, src, dst, w1_0, b1_0, w2_0, b2_0, agg);
    node_kernel<true><<<NB, 256, 0, stream>>>(x, agg, deg, root_0, bias_0, h);

    // layer 1
    hipMemsetAsync(agg, 0, (size_t)N_NODES * D_H * sizeof(float), stream);
    edge_kernel<<<EB, 256, 0, stream>>>(h, edge_attr, src, dst, w1_1, b1_1, w2_1, b2_1, agg);
    node_kernel<true><<<NB, 256, 0, stream>>>(h, agg, deg, root_1, bias_1, h2);

    // classifier
    cls_kernel<<<NB, 256, 0, stream>>>(h2, cls_w, cls_b, (float*)d_out);
}

// Round 2
// 163.205 us; speedup vs baseline: 4.8345x; 4.8345x over previous
//
#include <hip/hip_runtime.h>
#include <hip/hip_bf16.h>
#include <math.h>

#define N_NODES 20000
#define N_EDGES 200000
#define D_IN 32
#define D_H 32
#define D_OUT 8
#define E_DIM 16
#define NKE 17               // 16 h-columns + 1 folded b2 column (h=1)
#define NCOL (NKE * 32)      // 544
#define NTILE (NCOL / 16)    // 34 MFMA N-tiles

typedef __attribute__((ext_vector_type(8))) short bf16x8;
typedef __attribute__((ext_vector_type(4))) float f32x4;

__device__ __forceinline__ float elu_f(float v) { return v > 0.f ? v : expm1f(v); }

__device__ __forceinline__ short f2bf(float f) {
    union { __hip_bfloat16 h; short s; } u;
    u.h = __float2bfloat16(f);
    return u.s;
}

// ---------------- degree histogram (int) ----------------
__global__ __launch_bounds__(256)
void deg_kernel(const int* __restrict__ dst, int* __restrict__ deg) {
    int e = blockIdx.x * 256 + threadIdx.x;
    if (e < N_EDGES) atomicAdd(&deg[dst[e]], 1);
}

// ---------------- exclusive scan over 20000 degrees, single block ----------------
__global__ __launch_bounds__(1024)
void scan_kernel(const int* __restrict__ deg, int* __restrict__ rowptr, int* __restrict__ cursor) {
    __shared__ int part[1024];
    const int t = threadIdx.x;
    const int base = t * 20;
    int loc[20];
    int sum = 0;
    #pragma unroll
    for (int j = 0; j < 20; ++j) {
        int idx = base + j;
        int v = (idx < N_NODES) ? deg[idx] : 0;
        loc[j] = v;
        sum += v;
    }
    part[t] = sum;
    __syncthreads();
    for (int off = 1; off < 1024; off <<= 1) {
        int v = (t >= off) ? part[t - off] : 0;
        __syncthreads();
        part[t] += v;
        __syncthreads();
    }
    int run = part[t] - sum;  // exclusive prefix for this chunk
    #pragma unroll
    for (int j = 0; j < 20; ++j) {
        int idx = base + j;
        if (idx < N_NODES) { rowptr[idx] = run; cursor[idx] = run; run += loc[j]; }
    }
    if (t == 0) rowptr[N_NODES] = N_EDGES;
}

// ---------------- CSR fill ----------------
__global__ __launch_bounds__(256)
void fill_kernel(const int* __restrict__ dst, int* __restrict__ cursor, int* __restrict__ edge_order) {
    int e = blockIdx.x * 256 + threadIdx.x;
    if (e < N_EDGES) {
        int pos = atomicAdd(&cursor[dst[e]], 1);
        edge_order[pos] = e;
    }
}

// ---------------- build per-fragment swizzled B = [W2' | b2'] in bf16 ----------------
// B matrix: rows i=0..31 (x feature), cols c = k*32+o (k<16: W2[k][i*32+o]; k==16: b2[i*32+o])
// B_swz[n][lane][j] = B[(lane>>4)*8 + j][n*16 + (lane&15)]
__global__ __launch_bounds__(256)
void prep_kernel(const float* __restrict__ w2, const float* __restrict__ b2,
                 short* __restrict__ bswz) {
    for (int idx = blockIdx.x * 256 + threadIdx.x; idx < NTILE * 64 * 8; idx += gridDim.x * 256) {
        int j = idx & 7;
        int l = (idx >> 3) & 63;
        int n = idx >> 9;
        int i = (l >> 4) * 8 + j;
        int c = n * 16 + (l & 15);
        float v;
        if (c < 512) { int k = c >> 5, o = c & 31; v = w2[k * 1024 + i * 32 + o]; }
        else         { int o = c - 512;            v = b2[i * 32 + o]; }
        bswz[idx] = f2bf(v);
    }
}

// ---------------- fused edge kernel: edge-MLP + MFMA theta-GEMM + contraction ----------------
__global__ __launch_bounds__(256)
void edge_mfma_kernel(const float* __restrict__ xin,        // [N,32] node features (fp32)
                      const float* __restrict__ edge_attr,  // [E,16]
                      const int* __restrict__ src,
                      const short* __restrict__ bswz,       // [34][64][8] bf16
                      const float* __restrict__ w1,         // [16,16]
                      const float* __restrict__ b1,         // [16]
                      __hip_bfloat16* __restrict__ msg)     // [E,32] out
{
    __shared__ __align__(16) short bswz_s[NTILE * 64 * 8];  // 34816 B
    __shared__ __align__(16) float h_s[NKE][64];            // 4352 B  (col = wave*16 + eloc)
    __shared__ __align__(16) float w1_s[E_DIM * E_DIM];
    __shared__ float b1_s[E_DIM];

    const int t = threadIdx.x;
    for (int i = t; i < NTILE * 64; i += 256)               // 16B chunks
        ((int4*)bswz_s)[i] = ((const int4*)bswz)[i];
    for (int i = t; i < E_DIM * E_DIM; i += 256) w1_s[i] = w1[i];
    if (t < E_DIM) b1_s[t] = b1[t];
    __syncthreads();

    const int lane = t & 63;
    const int wave = t >> 6;
    const int e_base = blockIdx.x * 64 + wave * 16;
    const int eloc = lane & 15;
    const int kg = lane >> 4;  // 0..3
    const int e = e_base + eloc;

    // --- edge MLP: lane computes h[kg*4+kk][eloc], kk=0..3 (wave-private h_s columns) ---
    {
        float ea[E_DIM];
        const float4* eg = (const float4*)(edge_attr + (size_t)e * E_DIM);
        ((float4*)ea)[0] = eg[0]; ((float4*)ea)[1] = eg[1];
        ((float4*)ea)[2] = eg[2]; ((float4*)ea)[3] = eg[3];
        const float4 bv = *(const float4*)&b1_s[kg * 4];
        float acc0 = bv.x, acc1 = bv.y, acc2 = bv.z, acc3 = bv.w;
        #pragma unroll
        for (int j = 0; j < E_DIM; ++j) {
            const float4 wv = *(const float4*)&w1_s[j * E_DIM + kg * 4];
            acc0 += ea[j] * wv.x; acc1 += ea[j] * wv.y;
            acc2 += ea[j] * wv.z; acc3 += ea[j] * wv.w;
        }
        h_s[kg * 4 + 0][wave * 16 + eloc] = elu_f(acc0);
        h_s[kg * 4 + 1][wave * 16 + eloc] = elu_f(acc1);
        h_s[kg * 4 + 2][wave * 16 + eloc] = elu_f(acc2);
        h_s[kg * 4 + 3][wave * 16 + eloc] = elu_f(acc3);
        if (kg == 0) h_s[16][wave * 16 + eloc] = 1.0f;
    }

    // --- A fragment: A[row=eloc][kdim=kg*8+j] = x[src[e]][kg*8+j], bf16 ---
    bf16x8 a;
    {
        const int s = src[e];
        const float4 x0 = *(const float4*)(xin + (size_t)s * D_IN + kg * 8);
        const float4 x1 = *(const float4*)(xin + (size_t)s * D_IN + kg * 8 + 4);
        a[0] = f2bf(x0.x); a[1] = f2bf(x0.y); a[2] = f2bf(x0.z); a[3] = f2bf(x0.w);
        a[4] = f2bf(x1.x); a[5] = f2bf(x1.y); a[6] = f2bf(x1.z); a[7] = f2bf(x1.w);
    }

    // --- 34 N-tiles: U-tile = A·B_n, contract with h immediately ---
    float msgr[2][4] = {{0.f, 0.f, 0.f, 0.f}, {0.f, 0.f, 0.f, 0.f}};
    const f32x4 zero = {0.f, 0.f, 0.f, 0.f};
    #pragma unroll
    for (int n = 0; n < NTILE; ++n) {
        bf16x8 b = *(const bf16x8*)&bswz_s[(n * 64 + lane) * 8];
        f32x4 d = __builtin_amdgcn_mfma_f32_16x16x32_bf16(a, b, zero, 0, 0, 0);
        const int k = n >> 1;
        const int oh = n & 1;
        // D rows for this lane: (lane>>4)*4 + r  -> edges e_base + kg*4 + r
        const float4 hv = *(const float4*)&h_s[k][wave * 16 + kg * 4];
        msgr[oh][0] += hv.x * d[0];
        msgr[oh][1] += hv.y * d[1];
        msgr[oh][2] += hv.z * d[2];
        msgr[oh][3] += hv.w * d[3];
    }

    // --- store msg (bf16, linear, no atomics) ---
    __hip_bfloat16* mp = msg + (size_t)e_base * D_H;
    #pragma unroll
    for (int oh = 0; oh < 2; ++oh)
        #pragma unroll
        for (int r = 0; r < 4; ++r)
            mp[(kg * 4 + r) * D_H + oh * 16 + (lane & 15)] = __float2bfloat16(msgr[oh][r]);
}

// ---------------- aggregation: scatter-mean via CSR + root GEMM + bias + ELU ----------------
template<bool APPLY_ELU>
__global__ __launch_bounds__(256)
void agg_kernel(const float* __restrict__ xin,              // [N,32]
                const __hip_bfloat16* __restrict__ msg,     // [E,32]
                const int* __restrict__ rowptr,
                const int* __restrict__ edge_order,
                const float* __restrict__ root,             // [32,32]
                const float* __restrict__ bias,             // [32]
                float* __restrict__ out)                    // [N,32]
{
    __shared__ float root_s[D_H * D_H];
    __shared__ float bias_s[D_H];
    const int t = threadIdx.x;
    for (int i = t; i < D_H * D_H; i += 256) root_s[i] = root[i];
    if (t < D_H) bias_s[t] = bias[t];
    __syncthreads();

    const int lane = t & 63;
    const int wave = t >> 6;
    const int half = lane >> 5;
    const int o = lane & 31;
    const int n = blockIdx.x * 8 + wave * 2 + half;

    const int start = rowptr[n];
    const int end = rowptr[n + 1];
    float s = 0.f;
    for (int j = start; j < end; ++j) {
        int e = edge_order[j];
        s += __bfloat162float(msg[(size_t)e * D_H + o]);
    }
    const float inv = 1.f / fmaxf((float)(end - start), 1.f);
    float acc = s * inv + bias_s[o];
    const float xv = xin[(size_t)n * D_H + o];
    #pragma unroll
    for (int i = 0; i < D_H; ++i) {
        float xi = __shfl(xv, half * 32 + i);
        acc += xi * root_s[i * D_H + o];
    }
    out[(size_t)n * D_H + o] = APPLY_ELU ? elu_f(acc) : acc;
}

// ---------------- classifier ----------------
__global__ __launch_bounds__(256)
void cls_kernel(const float* __restrict__ h, const float* __restrict__ w,
                const float* __restrict__ b, float* __restrict__ out) {
    __shared__ float w_s[D_H * D_OUT];
    __shared__ float b_s[D_OUT];
    const int t = threadIdx.x;
    if (t < D_H * D_OUT) w_s[t] = w[t];
    if (t < D_OUT) b_s[t] = b[t];
    __syncthreads();

    const int n = blockIdx.x * 256 + t;
    if (n >= N_NODES) return;

    float xs[D_H];
    {
        const float4* xg = (const float4*)(h + (size_t)n * D_H);
        float4* xsv = (float4*)xs;
        #pragma unroll
        for (int i = 0; i < D_H / 4; ++i) xsv[i] = xg[i];
    }
    float o[D_OUT];
    #pragma unroll
    for (int j = 0; j < D_OUT; ++j) {
        float a = b_s[j];
        #pragma unroll
        for (int i = 0; i < D_H; ++i) a += xs[i] * w_s[i * D_OUT + j];
        o[j] = a;
    }
    float4* ov = (float4*)(out + (size_t)n * D_OUT);
    ov[0] = *(float4*)&o[0];
    ov[1] = *(float4*)&o[4];
}

extern "C" void kernel_launch(void* const* d_in, const int* in_sizes, int n_in,
                              void* d_out, int out_size, void* d_ws, size_t ws_size,
                              hipStream_t stream)
{
    const float* x          = (const float*)d_in[0];
    const float* edge_attr  = (const float*)d_in[1];
    const int*   edge_index = (const int*)d_in[2];
    const float* w1_0 = (const float*)d_in[3];
    const float* b1_0 = (const float*)d_in[4];
    const float* w2_0 = (const float*)d_in[5];
    const float* b2_0 = (const float*)d_in[6];
    const float* root_0 = (const float*)d_in[7];
    const float* bias_0 = (const float*)d_in[8];
    const float* w1_1 = (const float*)d_in[9];
    const float* b1_1 = (const float*)d_in[10];
    const float* w2_1 = (const float*)d_in[11];
    const float* b2_1 = (const float*)d_in[12];
    const float* root_1 = (const float*)d_in[13];
    const float* bias_1 = (const float*)d_in[14];
    const float* cls_w = (const float*)d_in[15];
    const float* cls_b = (const float*)d_in[16];

    const int* src = edge_index;
    const int* dst = edge_index + N_EDGES;

    char* ws = (char*)d_ws;
    int* deg_i      = (int*)ws;                       // 20000
    int* rowptr     = deg_i + N_NODES;                // 20001
    int* cursor     = rowptr + N_NODES + 1;           // 20000
    int* edge_order = cursor + N_NODES;               // 200000
    size_t off = ((size_t)(N_NODES * 3 + 1 + N_EDGES) * 4 + 15) & ~(size_t)15;
    short* bswz = (short*)(ws + off);                 // 34*64*8 bf16 = 34816 B
    off = (off + (size_t)NTILE * 64 * 8 * 2 + 15) & ~(size_t)15;
    __hip_bfloat16* msg = (__hip_bfloat16*)(ws + off);  // E*32 bf16 = 12.8 MB
    off = (off + (size_t)N_EDGES * D_H * 2 + 15) & ~(size_t)15;
    float* h  = (float*)(ws + off);                   // N*32 f32
    off += (size_t)N_NODES * D_H * 4;
    float* h2 = (float*)(ws + off);

    const int EB = (N_EDGES + 255) / 256;   // 782
    const int NB = (N_NODES + 255) / 256;   // 79

    hipMemsetAsync(deg_i, 0, (size_t)N_NODES * sizeof(int), stream);

    // CSR build (shared by both layers)
    deg_kernel<<<EB, 256, 0, stream>>>(dst, deg_i);
    scan_kernel<<<1, 1024, 0, stream>>>(deg_i, rowptr, cursor);
    fill_kernel<<<EB, 256, 0, stream>>>(dst, cursor, edge_order);

    // layer 0
    prep_kernel<<<68, 256, 0, stream>>>(w2_0, b2_0, bswz);
    edge_mfma_kernel<<<N_EDGES / 64, 256, 0, stream>>>(x, edge_attr, src, bswz, w1_0, b1_0, msg);
    agg_kernel<true><<<N_NODES / 8, 256, 0, stream>>>(x, msg, rowptr, edge_order, root_0, bias_0, h);

    // layer 1
    prep_kernel<<<68, 256, 0, stream>>>(w2_1, b2_1, bswz);
    edge_mfma_kernel<<<N_EDGES / 64, 256, 0, stream>>>(h, edge_attr, src, bswz, w1_1, b1_1, msg);
    agg_kernel<true><<<N_NODES / 8, 256, 0, stream>>>(h, msg, rowptr, edge_order, root_1, bias_1, h2);

    // classifier
    cls_kernel<<<NB, 256, 0, stream>>>(h2, cls_w, cls_b, (float*)d_out);
}